// Round 3
// baseline (710.264 us; speedup 1.0000x reference)
//
#include <hip/hip_runtime.h>
#include <cmath>

// ---------------------------------------------------------------------------
// DynamicProbSparseAttention: B=4, L=8192, D=1024, H=16, dk=64
//   - bf16 MFMA GEMM for Q,K,V; Q never materialized: sparsity scores are
//     computed in the GEMM epilogue (quad-of-16 lanes hold whole Q rows)
//   - R7: 2-barriers-per-TILE + register prefetch. R6's per-phase pre-MFMA
//     barrier kept waves lockstep (LDS reads serialized vs MFMA, 33.6% util).
//     Now: mid-tile barrier after p1-MFMA (B-region protect: arrival implies
//     all waves' B reads retired) + tile-end vmcnt(4)+barrier (ledger
//     unchanged). A-frags prefetched one phase ahead; only 2 memory-clobber
//     fences per tile so the compiler schedules ds_reads under MFMA clusters.
//   - natural block order; XCD swizzle measured WORSE (R4)
//   - top-16 candidate prefilter (k_cand, fused u-stats)
//   - exact fp64 rescore of candidates (k_rescore), top-10 select (k_select)
//   - sparse attention: single-pass K/V, 2048 blocks
//   - output = broadcast bo + fused merge+scatter of (attn_out @ wo_head.T)
// ---------------------------------------------------------------------------

typedef short     s16x8 __attribute__((ext_vector_type(8)));
typedef unsigned short u16x8 __attribute__((ext_vector_type(8)));
typedef unsigned short u16x4 __attribute__((ext_vector_type(4)));
typedef float     f32x4 __attribute__((ext_vector_type(4)));

__device__ __forceinline__ unsigned short f2bf(float f) {
    unsigned u = __float_as_uint(f);
    u += 0x7fffu + ((u >> 16) & 1u);   // round-to-nearest-even
    return (unsigned short)(u >> 16);
}
__device__ __forceinline__ float bf2f(unsigned short s) {
    return __uint_as_float(((unsigned)s) << 16);
}

__device__ __forceinline__ void async16(const void* g, void* l) {
    __builtin_amdgcn_global_load_lds(
        (const __attribute__((address_space(1))) void*)g,
        (__attribute__((address_space(3))) void*)l, 16, 0, 0);
}

// ---------------- fused convert kernel (x + 3 weights) ----------------
__global__ void k_conv(const float* __restrict__ x, const float* __restrict__ wq,
                       const float* __restrict__ wk, const float* __restrict__ wv,
                       unsigned short* __restrict__ xb, unsigned short* __restrict__ wb) {
    size_t i = (size_t)blockIdx.x * 256 + threadIdx.x;    // 8388608 + 786432 float4s
    if (i < 8388608) {
        float4 v = ((const float4*)x)[i];
        ushort4 o; o.x = f2bf(v.x); o.y = f2bf(v.y); o.z = f2bf(v.z); o.w = f2bf(v.w);
        ((ushort4*)xb)[i] = o;
    } else {
        size_t j = i - 8388608;
        size_t wsel = j >> 18, rem = j & 262143;
        const float* src = wsel == 0 ? wq : (wsel == 1 ? wk : wv);
        float4 v = ((const float4*)src)[rem];
        ushort4 o; o.x = f2bf(v.x); o.y = f2bf(v.y); o.z = f2bf(v.z); o.w = f2bf(v.w);
        ((ushort4*)wb)[j] = o;
    }
}

// ---- helpers for the GEMM main loop (forceinline, constant indices) ----
__device__ __forceinline__ void rdA(s16x8 (&dst)[2][2], const char* A_, int r0,
                                    int qk0, int qk1) {
    dst[0][0] = *(const s16x8*)(A_ + r0 * 2048 + qk0);
    dst[0][1] = *(const s16x8*)(A_ + r0 * 2048 + qk1);
    dst[1][0] = *(const s16x8*)(A_ + (r0 + 1) * 2048 + qk0);
    dst[1][1] = *(const s16x8*)(A_ + (r0 + 1) * 2048 + qk1);
}
__device__ __forceinline__ void mfma8(f32x4 (&acc)[8][4], int i0, int i1,
                                      const s16x8 (&aa)[2][2], const s16x8 (&bfr)[4][2]) {
    __builtin_amdgcn_s_setprio(1);
#pragma unroll
    for (int kk = 0; kk < 2; ++kk)
#pragma unroll
        for (int n = 0; n < 4; ++n) {
            acc[i0][n] = __builtin_amdgcn_mfma_f32_16x16x32_bf16(aa[0][kk], bfr[n][kk], acc[i0][n], 0, 0, 0);
            acc[i1][n] = __builtin_amdgcn_mfma_f32_16x16x32_bf16(aa[1][kk], bfr[n][kk], acc[i1][n], 0, 0, 0);
        }
    __builtin_amdgcn_s_setprio(0);
}

// ---------------- fused QKV GEMM (C = x @ W^T + b), bf16 MFMA ----------------
// 256x256 tile, BK=64, 8 waves (2x4), 2-barrier-per-tile pipelined schedule.
// wsel==0 (Q): epilogue computes sparsity scores, Q never stored.
//
// LDS map (bytes): buf(0/65536) | A:+0, B:+32768 | half(128 rows):+16384
//   row-major [128][128B] per half; swizzle: data (r,c) at slot c^((r&7)<<4).
__global__ __launch_bounds__(512, 2) void k_gemm_qkv(
    const unsigned short* __restrict__ xb, const unsigned short* __restrict__ wb,
    const float* __restrict__ bq, const float* __restrict__ bk, const float* __restrict__ bv,
    unsigned short* __restrict__ Kb, unsigned short* __restrict__ Vb,
    float* __restrict__ scores)
{
    extern __shared__ char ldsb[];
    int bid = blockIdx.x;
    int mt = bid / 12, ntile = bid % 12;          // 12 blocks share one x-panel
    int wsel = ntile >> 2, ntq = ntile & 3;
    int tid = threadIdx.x, wid = tid >> 6, lane = tid & 63;
    int wm = wid >> 2, wn = wid & 3;              // wave -> 128x64 output
    int ml = lane & 15, quad = lane >> 4;

    const char* xg = (const char*)(xb + (size_t)mt * 256 * 1024);
    const char* wg = (const char*)(wb + (size_t)ntile * 256 * 1024);
    // A(h,t): xg + h*262144 + t*128 ; B(h,t): wg + h*262144 + t*128

    // staging lane constants (pre-swizzled global source)
    int rg0  = wid * 2;
    int rsub = lane >> 3;                         // row within 8-row group
    int cswz = ((lane & 7) ^ rsub) << 4;          // swizzled 16B col slot

#define STAGE(gbase_, roff_) do {                                          \
        const char* _g = (gbase_) + (size_t)(rg0 * 8 + rsub) * 2048 + cswz; \
        char* _l = ldsb + (roff_) + rg0 * 1024;                             \
        async16(_g, _l);                                                    \
        async16(_g + 8 * 2048, _l + 1024);                                  \
    } while (0)

    // ds_read lane constants: addr = base + m*2048 + (q0 ^ (kk<<6))
    int q0  = (quad * 16) ^ ((ml & 7) << 4);
    int qk0 = q0, qk1 = q0 ^ 64;
    int aconst = wm * 16384 + ml * 128;
    int bconst = 32768 + (wn >> 1) * 16384 + (wn & 1) * 8192 + ml * 128;

    f32x4 acc[8][4] = {};

    // ---- prologue: B(t0) h0,h1 ; A(t0) h0,h1 ; B(t1) h0,h1 -> vmcnt(4)
    STAGE(wg,                32768);
    STAGE(wg + 262144,       32768 + 16384);
    STAGE(xg,                0);
    STAGE(xg + 262144,       16384);
    STAGE(wg + 128,          65536 + 32768);
    STAGE(wg + 262144 + 128, 65536 + 32768 + 16384);
    asm volatile("s_waitcnt vmcnt(4)" ::: "memory");
    __builtin_amdgcn_s_barrier();
    asm volatile("" ::: "memory");

    for (int t = 0; t < 16; ++t) {
        int buf  = (t & 1) << 16;
        int nbuf = buf ^ 65536;
        const char* A_ = ldsb + buf + aconst;
        const char* B_ = ldsb + buf + bconst;
        s16x8 bfr[4][2];
#pragma unroll
        for (int n = 0; n < 4; ++n) {
            bfr[n][0] = *(const s16x8*)(B_ + n * 2048 + qk0);
            bfr[n][1] = *(const s16x8*)(B_ + n * 2048 + qk1);
        }
        s16x8 af[2][2], ag[2][2];
        rdA(af, A_, 0, qk0, qk1);
        if (t < 15) STAGE(xg + (size_t)(t + 1) * 128, nbuf);
        rdA(ag, A_, 2, qk0, qk1);                 // prefetch p1 under p0-MFMA
        mfma8(acc, 0, 1, af, bfr);                // p0
        if (t < 15) STAGE(xg + 262144 + (size_t)(t + 1) * 128, nbuf + 16384);
        rdA(af, A_, 4, qk0, qk1);                 // prefetch p2 under p1-MFMA
        mfma8(acc, 2, 3, ag, bfr);                // p1
        // -- mid-tile barrier (B-region protect): arrival implies every
        //    wave's B/A0/A1 ds_reads retired (consumed by its p0/p1 MFMAs)
        asm volatile("" ::: "memory");
        __builtin_amdgcn_s_barrier();
        asm volatile("" ::: "memory");
        if (t < 14) STAGE(wg + (size_t)(t + 2) * 128, buf + 32768);
        rdA(ag, A_, 6, qk0, qk1);                 // prefetch p3 under p2-MFMA
        mfma8(acc, 4, 5, af, bfr);                // p2
        if (t < 14) STAGE(wg + 262144 + (size_t)(t + 2) * 128, buf + 32768 + 16384);
        mfma8(acc, 6, 7, ag, bfr);                // p3
        // -- tile boundary: counted wait (leaves B(t+2) in flight), barrier
        //    so all waves' loads for tile t+1 are jointly landed
        if (t <= 13)      asm volatile("s_waitcnt vmcnt(4)" ::: "memory");
        else if (t == 14) asm volatile("s_waitcnt vmcnt(0)" ::: "memory");
        asm volatile("" ::: "memory");
        __builtin_amdgcn_s_barrier();
        asm volatile("" ::: "memory");
    }
#undef STAGE

    float bvv[4];
    const float* bias = wsel == 0 ? bq : (wsel == 1 ? bk : bv);
    int colbase = ntq * 256 + wn * 64;
#pragma unroll
    for (int n = 0; n < 4; ++n) bvv[n] = bias[colbase + n * 16 + ml];

    if (wsel == 0) {
        // score epilogue: quad's 16 lanes hold full 64-wide Q rows of head hh
        int hh = ntq * 4 + wn;
#pragma unroll
        for (int m = 0; m < 8; ++m) {
#pragma unroll
            for (int r = 0; r < 4; ++r) {
                float q0v = acc[m][0][r] + bvv[0];
                float q1v = acc[m][1][r] + bvv[1];
                float q2v = acc[m][2][r] + bvv[2];
                float q3v = acc[m][3][r] + bvv[3];
                float mx = fmaxf(fmaxf(q0v, q1v), fmaxf(q2v, q3v));
                float sm = q0v + q1v + q2v + q3v;
                float ss = q0v * q0v + q1v * q1v + q2v * q2v + q3v * q3v;
#pragma unroll
                for (int off = 1; off < 16; off <<= 1) {
                    mx = fmaxf(mx, __shfl_xor(mx, off));
                    sm += __shfl_xor(sm, off);
                    ss += __shfl_xor(ss, off);
                }
                float e0 = expf(q0v - mx), e1 = expf(q1v - mx);
                float e2 = expf(q2v - mx), e3 = expf(q3v - mx);
                float S = e0 + e1 + e2 + e3;
#pragma unroll
                for (int off = 1; off < 16; off <<= 1) S += __shfl_xor(S, off);
                float is = 1.f / S;
                float p0 = e0 * is, p1 = e1 * is, p2 = e2 * is, p3 = e3 * is;
                float ent = -p0 * logf(p0 + 1e-9f) - p1 * logf(p1 + 1e-9f)
                            - p2 * logf(p2 + 1e-9f) - p3 * logf(p3 + 1e-9f);
                float mean = sm * (1.f / 64.f);
                float d0 = q0v - mean, d1 = q1v - mean, d2 = q2v - mean, d3 = q3v - mean;
                float var = d0 * d0 + d1 * d1 + d2 * d2 + d3 * d3;
#pragma unroll
                for (int off = 1; off < 16; off <<= 1) {
                    ent += __shfl_xor(ent, off);
                    var += __shfl_xor(var, off);
                }
                if (ml == 0) {
                    float sc = 0.5f * sqrtf(ss) + 0.3f * ent + 0.2f * (var * (1.f / 63.f));
                    int row = mt * 256 + wm * 128 + m * 16 + quad * 4 + r;
                    scores[(size_t)(((row >> 13) << 4) + hh) * 8192 + (row & 8191)] = sc;
                }
            }
        }
    } else {
        unsigned short* outp = wsel == 1 ? Kb : Vb;
#pragma unroll
        for (int m = 0; m < 8; ++m) {
            int grow0 = mt * 256 + wm * 128 + m * 16 + quad * 4;
#pragma unroll
            for (int n = 0; n < 4; ++n) {
                int gcol = colbase + n * 16 + ml;
#pragma unroll
                for (int r = 0; r < 4; ++r)
                    outp[(size_t)(grow0 + r) * 1024 + gcol] = f2bf(acc[m][n][r] + bvv[n]);
            }
        }
    }
}

// ---------------- top-16 candidates + (h==0) u-stats, per pair ----------------
__global__ __launch_bounds__(1024) void k_cand(const float* __restrict__ scores,
                                               int* __restrict__ cand, int* __restrict__ u)
{
    int pair = blockIdx.x; int t = threadIdx.x;
    __shared__ float  s_lds[8192];
    __shared__ double dred[1024];
    __shared__ float  wvv[16];
    __shared__ int    wii[16];
    const float* sp = scores + (size_t)pair * 8192;
    for (int i = t; i < 8192; i += 1024) s_lds[i] = sp[i];
    __syncthreads();

    if ((pair & 15) == 0) {     // head 0: compute u[b] from these scores
        double a0 = 0;
#pragma unroll
        for (int k = 0; k < 8; ++k) a0 += (double)s_lds[t + k * 1024];
        dred[t] = a0; __syncthreads();
        for (int st = 512; st > 0; st >>= 1) { if (t < st) dred[t] += dred[t + st]; __syncthreads(); }
        double mean = dred[0] / 8192.0;
        __syncthreads();
        double a1 = 0;
#pragma unroll
        for (int k = 0; k < 8; ++k) { double d = (double)s_lds[t + k * 1024] - mean; a1 += d * d; }
        dred[t] = a1; __syncthreads();
        for (int st = 512; st > 0; st >>= 1) { if (t < st) dred[t] += dred[t + st]; __syncthreads(); }
        if (t == 0) {
            double sd = sqrt(dred[0] / 8191.0);
            double ratio = sd / (mean + 1e-6) * 10.0;
            int f = (int)rint(ratio);
            f = f < 3 ? 3 : (f > 10 ? 10 : f);
            u[pair >> 4] = f;
        }
        __syncthreads();
    }

    for (int it = 0; it < 16; ++it) {
        float bv = -1e30f; int bi = 0x7fffffff;
#pragma unroll
        for (int k = 0; k < 8; ++k) {
            int i = t + k * 1024;
            float v = s_lds[i];
            if (v > bv || (v == bv && i < bi)) { bv = v; bi = i; }
        }
#pragma unroll
        for (int off = 32; off > 0; off >>= 1) {
            float ov = __shfl_down(bv, off);
            int   oi = __shfl_down(bi, off);
            if (ov > bv || (ov == bv && oi < bi)) { bv = ov; bi = oi; }
        }
        if ((t & 63) == 0) { wvv[t >> 6] = bv; wii[t >> 6] = bi; }
        __syncthreads();
        if (t == 0) {
            float fv = wvv[0]; int fi = wii[0];
            for (int k = 1; k < 16; ++k)
                if (wvv[k] > fv || (wvv[k] == fv && wii[k] < fi)) { fv = wvv[k]; fi = wii[k]; }
            cand[pair * 16 + it] = fi;
            s_lds[fi] = -1e30f;
        }
        __syncthreads();
    }
}

// ---------------- exact fp64 rescore, one block per (pair,candidate) ----------------
__global__ __launch_bounds__(256) void k_rescore(
    const int* __restrict__ cand, const float* __restrict__ x,
    const float* __restrict__ wq, const float* __restrict__ bq,
    double* __restrict__ cscore, float* __restrict__ cq)
{
    int bid = blockIdx.x;             // pair*16 + c
    int pair = bid >> 4;
    int b = pair >> 4, h = pair & 15;
    int t = threadIdx.x;
    __shared__ float  xrow[1024];
    __shared__ double dred[256];
    __shared__ double qrow[64];

    int l = cand[bid];
    const float* xr = x + ((size_t)b * 8192 + l) * 1024;
    for (int i = t; i < 1024; i += 256) xrow[i] = xr[i];
    __syncthreads();

    int d = t >> 2, ks = t & 3;
    const float* wr = wq + (size_t)(h * 64 + d) * 1024 + ks * 256;
    const float* xs = xrow + ks * 256;
    double p = 0;
    for (int k = 0; k < 256; k += 4) {
        float4 w4 = *(const float4*)(wr + k);
        float4 x4 = *(const float4*)(xs + k);
        p += (double)w4.x * x4.x + (double)w4.y * x4.y +
             (double)w4.z * x4.z + (double)w4.w * x4.w;
    }
    dred[t] = p; __syncthreads();
    if ((t & 3) == 0)
        qrow[t >> 2] = dred[t] + dred[t + 1] + dred[t + 2] + dred[t + 3] + (double)bq[h * 64 + (t >> 2)];
    __syncthreads();

    if (t < 64) {
        double q = qrow[t];
        cq[(size_t)bid * 64 + t] = (float)q;
        double m = q;
#pragma unroll
        for (int off = 32; off > 0; off >>= 1) m = fmax(m, __shfl_down(m, off));
        m = __shfl(m, 0);
        double e = exp(q - m);
        double sum = q, sumsq = q * q, S = e;
#pragma unroll
        for (int off = 32; off > 0; off >>= 1) {
            sum += __shfl_down(sum, off);
            sumsq += __shfl_down(sumsq, off);
            S += __shfl_down(S, off);
        }
        sum = __shfl(sum, 0); sumsq = __shfl(sumsq, 0); S = __shfl(S, 0);
        double pp = e / S;
        double entc = -pp * log(pp + 1e-9);
        double mean = sum / 64.0;
        double dv = q - mean;
        double varc = dv * dv;
#pragma unroll
        for (int off = 32; off > 0; off >>= 1) {
            entc += __shfl_down(entc, off);
            varc += __shfl_down(varc, off);
        }
        if (t == 0)
            cscore[bid] = 0.5 * sqrt(sumsq) + 0.3 * entc + 0.2 * (varc / 63.0);
    }
}

// ---------------- top-10-of-16 select ----------------
__global__ void k_select(const int* __restrict__ cand, const double* __restrict__ cscore,
                         const float* __restrict__ cq,
                         int* __restrict__ sel, float* __restrict__ selq)
{
    int pair = blockIdx.x; int t = threadIdx.x;   // 64 threads
    __shared__ int order[10];
    if (t == 0) {
        bool used[16] = {};
        for (int r = 0; r < 10; ++r) {
            int best = -1;
            for (int c = 0; c < 16; ++c) {
                if (used[c]) continue;
                int ic = pair * 16 + c;
                if (best < 0 || cscore[ic] > cscore[pair * 16 + best] ||
                    (cscore[ic] == cscore[pair * 16 + best] && cand[ic] < cand[pair * 16 + best]))
                    best = c;
            }
            used[best] = true; order[r] = best;
            sel[pair * 10 + r] = cand[pair * 16 + best];
        }
    }
    __syncthreads();
    for (int r = 0; r < 10; ++r)
        selq[((size_t)pair * 10 + r) * 64 + t] = cq[((size_t)pair * 16 + order[r]) * 64 + t];
}

// ---------------- attention partials: one K/V pass, 256-row chunks ----------------
__global__ __launch_bounds__(256) void k_attn_part(
    const unsigned short* __restrict__ Kb, const unsigned short* __restrict__ Vb,
    const float* __restrict__ selq, const int* __restrict__ u,
    float* __restrict__ part)
{
    int bid = blockIdx.x;
    int pair = bid >> 5, chunk = bid & 31;
    int b = pair >> 4, h = pair & 15;
    int uu = u[b];
    int t = threadIdx.x, wave = t >> 6, lane = t & 63;

    __shared__ float q_sh[10][64];
    __shared__ float w_sh[10][256];
    __shared__ unsigned short V_sh[256][68];
    __shared__ float mc_sh[10][2], Sc_sh[10][2];

    size_t kvbase = ((size_t)b * 8192 + (size_t)chunk * 256) * 1024 + h * 64;

    for (int i = t; i < uu * 64; i += 256)
        q_sh[i >> 6][i & 63] = selq[(size_t)pair * 640 + i] * 0.125f;

    const u16x8* kr = (const u16x8*)(Kb + kvbase + (size_t)t * 1024);
    const u16x8* vr = (const u16x8*)(Vb + kvbase + (size_t)t * 1024);
    u16x8 vreg[8];
#pragma unroll
    for (int k8 = 0; k8 < 8; ++k8) vreg[k8] = vr[k8];
#pragma unroll
    for (int k8 = 0; k8 < 8; ++k8) {
        *(u16x4*)&V_sh[t][k8 * 8]     = { vreg[k8][0], vreg[k8][1], vreg[k8][2], vreg[k8][3] };
        *(u16x4*)&V_sh[t][k8 * 8 + 4] = { vreg[k8][4], vreg[k8][5], vreg[k8][6], vreg[k8][7] };
    }
    float krow[64];
#pragma unroll
    for (int k8 = 0; k8 < 8; ++k8) {
        u16x8 kv = kr[k8];
#pragma unroll
        for (int e = 0; e < 8; ++e) krow[k8 * 8 + e] = bf2f(kv[e]);
    }
    __syncthreads();

    for (int rr = 0; rr < uu; ++rr) {
        const float4* qp = (const float4*)q_sh[rr];
        float acc = 0.f;
#pragma unroll
        for (int i4 = 0; i4 < 16; ++i4) {
            float4 q4 = qp[i4];
            acc += q4.x * krow[i4 * 4] + q4.y * krow[i4 * 4 + 1] +
                   q4.z * krow[i4 * 4 + 2] + q4.w * krow[i4 * 4 + 3];
        }
        w_sh[rr][t] = acc;
    }
    __syncthreads();

    for (int rr = wave; rr < uu; rr += 4) {
        float4 wv = *(const float4*)&w_sh[rr][lane * 4];
        float m4 = fmaxf(fmaxf(wv.x, wv.y), fmaxf(wv.z, wv.w));
#pragma unroll
        for (int off = 16; off > 0; off >>= 1) m4 = fmaxf(m4, __shfl_xor(m4, off));
        float e0 = expf(wv.x - m4), e1 = expf(wv.y - m4);
        float e2 = expf(wv.z - m4), e3 = expf(wv.w - m4);
        float s = e0 + e1 + e2 + e3;
#pragma unroll
        for (int off = 16; off > 0; off >>= 1) s += __shfl_xor(s, off);
        float4 ev = { e0, e1, e2, e3 };
        *(float4*)&w_sh[rr][lane * 4] = ev;
        if ((lane & 31) == 0) { int jh = lane >> 5; mc_sh[rr][jh] = m4; Sc_sh[rr][jh] = s; }
    }
    __syncthreads();

    int jh = t >> 7, tt = t & 127, dp = tt & 31;
    for (int rr = tt >> 5; rr < uu; rr += 4) {
        float o0 = 0.f, o1 = 0.f;
        int j0 = jh * 128;
        for (int j = j0; j < j0 + 128; j += 4) {
            float4 w4 = *(const float4*)&w_sh[rr][j];
#pragma unroll
            for (int jj = 0; jj < 4; ++jj) {
                unsigned v = *(const unsigned*)&V_sh[j + jj][dp * 2];
                float w1 = jj == 0 ? w4.x : (jj == 1 ? w4.y : (jj == 2 ? w4.z : w4.w));
                o0 += w1 * __uint_as_float(v << 16);
                o1 += w1 * __uint_as_float(v & 0xffff0000u);
            }
        }
        float* pp = part + (((size_t)pair * 10 + rr) * 64 + chunk * 2 + jh) * 66;
        float2 o2 = { o0, o1 };
        *(float2*)&pp[2 + dp * 2] = o2;
        if (dp == 0) { pp[0] = mc_sh[rr][jh]; pp[1] = Sc_sh[rr][jh]; }
    }
}

// ---------------- output: broadcast bias ----------------
__global__ void k_bias(const float* __restrict__ bo, float* __restrict__ out) {
    size_t i = (size_t)blockIdx.x * 256 + threadIdx.x;   // 8388608 float4s
    int col4 = (int)(i & 255);
    ((float4*)out)[i] = ((const float4*)bo)[col4];
}

// ---------------- fused merge + sparse scatter ----------------
__global__ __launch_bounds__(256) void k_mergescatter(
    const float* __restrict__ part, const int* __restrict__ sel,
    const int* __restrict__ u, const float* __restrict__ wo,
    float* __restrict__ out)
{
    int idx = blockIdx.x; int pair = idx / 10; int r = idx % 10;
    int b = pair >> 4, h = pair & 15;
    if (r >= u[b]) return;
    int t = threadIdx.x;
    __shared__ float a_sh[64];
    if (t < 64) {
        const float* base = part + ((size_t)pair * 10 + r) * 64 * 66;
        float m = -1e30f;
        for (int c = 0; c < 64; ++c) m = fmaxf(m, base[c * 66]);
        float S = 0, o = 0;
        for (int c = 0; c < 64; ++c) {
            float f = expf(base[c * 66] - m);
            S += f * base[c * 66 + 1];
            o += f * base[c * 66 + 2 + t];
        }
        a_sh[t] = o / S;
    }
    __syncthreads();
    int l = sel[pair * 10 + r];
    float* orow = out + ((size_t)b * 8192 + l) * 1024;
    for (int j = t; j < 1024; j += 256) {
        const float* wr = wo + (size_t)j * 1024 + h * 64;
        float acc = 0;
#pragma unroll
        for (int d = 0; d < 64; d += 4) {
            float4 w4 = *(const float4*)(wr + d);
            acc += a_sh[d] * w4.x + a_sh[d + 1] * w4.y + a_sh[d + 2] * w4.z + a_sh[d + 3] * w4.w;
        }
        atomicAdd(orow + j, acc);
    }
}

// ---------------- workspace layout ----------------
static constexpr size_t OFF_XB    = 0;                        // 67108864
static constexpr size_t OFF_WB    = OFF_XB + 67108864;        // 6291456
static constexpr size_t OFF_KB    = OFF_WB + 6291456;         // 67108864
static constexpr size_t OFF_VB    = OFF_KB + 67108864;        // 67108864
static constexpr size_t OFF_SC    = OFF_VB + 67108864;        // 2097152
static constexpr size_t OFF_U     = OFF_SC + 2097152;         // 256
static constexpr size_t OFF_SEL   = OFF_U + 256;              // 4096
static constexpr size_t OFF_SELQ  = OFF_SEL + 4096;           // 163840
static constexpr size_t OFF_PART  = OFF_SELQ + 163840;        // 64*10*64*66*4 = 10813440
static constexpr size_t OFF_CAND  = OFF_PART + 10813440;      // 4096
static constexpr size_t OFF_CSC   = OFF_CAND + 4096;          // 8192
static constexpr size_t OFF_CQ    = OFF_CSC + 8192;           // 262144
static constexpr size_t WS_NEED   = OFF_CQ + 262144;

extern "C" void kernel_launch(void* const* d_in, const int* in_sizes, int n_in,
                              void* d_out, int out_size, void* d_ws, size_t ws_size,
                              hipStream_t stream)
{
    const float* x  = (const float*)d_in[0];
    const float* wq = (const float*)d_in[1];
    const float* bq = (const float*)d_in[2];
    const float* wk = (const float*)d_in[3];
    const float* bk = (const float*)d_in[4];
    const float* wv = (const float*)d_in[5];
    const float* bv = (const float*)d_in[6];
    const float* wo = (const float*)d_in[7];
    const float* bo = (const float*)d_in[8];
    float* out = (float*)d_out;

    if (ws_size < WS_NEED) return;

    char* ws = (char*)d_ws;
    unsigned short* xb = (unsigned short*)(ws + OFF_XB);
    unsigned short* wb = (unsigned short*)(ws + OFF_WB);
    unsigned short* Kb = (unsigned short*)(ws + OFF_KB);
    unsigned short* Vb = (unsigned short*)(ws + OFF_VB);
    float*  scores = (float*)(ws + OFF_SC);
    int*    u      = (int*)(ws + OFF_U);
    int*    sel    = (int*)(ws + OFF_SEL);
    float*  selq   = (float*)(ws + OFF_SELQ);
    float*  part   = (float*)(ws + OFF_PART);
    int*    cand   = (int*)(ws + OFF_CAND);
    double* cscore = (double*)(ws + OFF_CSC);
    float*  cq     = (float*)(ws + OFF_CQ);

    k_conv        <<<35840, 256,  0,      stream>>>(x, wq, wk, wv, xb, wb);
    k_gemm_qkv    <<<1536,  512,  131072, stream>>>(xb, wb, bq, bk, bv, Kb, Vb, scores);
    k_cand        <<<64,    1024, 0,      stream>>>(scores, cand, u);
    k_rescore     <<<1024,  256,  0,      stream>>>(cand, x, wq, bq, cscore, cq);
    k_select      <<<64,    64,   0,      stream>>>(cand, cscore, cq, sel, selq);
    k_attn_part   <<<2048,  256,  0,      stream>>>(Kb, Vb, selq, u, part);
    k_bias        <<<32768, 256,  0,      stream>>>(bo, out);
    k_mergescatter<<<640,   256,  0,      stream>>>(part, sel, u, wo, out);
}

// Round 4
// 697.640 us; speedup vs baseline: 1.0181x; 1.0181x over previous
//
#include <hip/hip_runtime.h>
#include <cmath>

// ---------------------------------------------------------------------------
// DynamicProbSparseAttention: B=4, L=8192, D=1024, H=16, dk=64
//   - bf16 MFMA GEMM for Q,K,V; Q never materialized: sparsity scores are
//     computed in the GEMM epilogue (quad-of-16 lanes hold whole Q rows)
//   - R8: deeper staging pipeline. R2/R3 identical (272us, 33% MfmaUtil)
//     despite different barrier/prefetch structure -> limiter is the
//     tile-end vmcnt stall (A(t+1) staged and waited within the same tile;
//     staging path runs ~5.8 TB/s aggregate -> load latency >> 900cyc).
//     Now: A triple-buffered (3x32KB), B double-buffered (2x32KB), 160 KiB
//     LDS total (1 block/CU regardless). Tile t stages A(t+2) at p0/p1 and
//     B(t+2) at p2/p3; tile-end vmcnt(8) drains only loads issued one full
//     tile earlier (~2x slack). 2 barriers/tile (mid = B-region protect,
//     end = joint residency). T2 swizzle kept (conflicts measured 0).
//   - natural block order; XCD swizzle measured WORSE (R4)
//   - top-16 candidate prefilter (k_cand, fused u-stats)
//   - exact fp64 rescore of candidates (k_rescore), top-10 select (k_select)
//   - sparse attention: single-pass K/V, 2048 blocks
//   - output = broadcast bo + fused merge+scatter of (attn_out @ wo_head.T)
// ---------------------------------------------------------------------------

typedef short     s16x8 __attribute__((ext_vector_type(8)));
typedef unsigned short u16x8 __attribute__((ext_vector_type(8)));
typedef unsigned short u16x4 __attribute__((ext_vector_type(4)));
typedef float     f32x4 __attribute__((ext_vector_type(4)));

__device__ __forceinline__ unsigned short f2bf(float f) {
    unsigned u = __float_as_uint(f);
    u += 0x7fffu + ((u >> 16) & 1u);   // round-to-nearest-even
    return (unsigned short)(u >> 16);
}
__device__ __forceinline__ float bf2f(unsigned short s) {
    return __uint_as_float(((unsigned)s) << 16);
}

__device__ __forceinline__ void async16(const void* g, void* l) {
    __builtin_amdgcn_global_load_lds(
        (const __attribute__((address_space(1))) void*)g,
        (__attribute__((address_space(3))) void*)l, 16, 0, 0);
}

// ---------------- fused convert kernel (x + 3 weights) ----------------
__global__ void k_conv(const float* __restrict__ x, const float* __restrict__ wq,
                       const float* __restrict__ wk, const float* __restrict__ wv,
                       unsigned short* __restrict__ xb, unsigned short* __restrict__ wb) {
    size_t i = (size_t)blockIdx.x * 256 + threadIdx.x;    // 8388608 + 786432 float4s
    if (i < 8388608) {
        float4 v = ((const float4*)x)[i];
        ushort4 o; o.x = f2bf(v.x); o.y = f2bf(v.y); o.z = f2bf(v.z); o.w = f2bf(v.w);
        ((ushort4*)xb)[i] = o;
    } else {
        size_t j = i - 8388608;
        size_t wsel = j >> 18, rem = j & 262143;
        const float* src = wsel == 0 ? wq : (wsel == 1 ? wk : wv);
        float4 v = ((const float4*)src)[rem];
        ushort4 o; o.x = f2bf(v.x); o.y = f2bf(v.y); o.z = f2bf(v.z); o.w = f2bf(v.w);
        ((ushort4*)wb)[j] = o;
    }
}

// ---- helpers for the GEMM main loop (forceinline, constant indices) ----
__device__ __forceinline__ void rdA(s16x8 (&dst)[2][2], const char* A_, int r0,
                                    int qk0, int qk1) {
    dst[0][0] = *(const s16x8*)(A_ + r0 * 2048 + qk0);
    dst[0][1] = *(const s16x8*)(A_ + r0 * 2048 + qk1);
    dst[1][0] = *(const s16x8*)(A_ + (r0 + 1) * 2048 + qk0);
    dst[1][1] = *(const s16x8*)(A_ + (r0 + 1) * 2048 + qk1);
}
__device__ __forceinline__ void mfma8(f32x4 (&acc)[8][4], int i0, int i1,
                                      const s16x8 (&aa)[2][2], const s16x8 (&bfr)[4][2]) {
    __builtin_amdgcn_s_setprio(1);
#pragma unroll
    for (int kk = 0; kk < 2; ++kk)
#pragma unroll
        for (int n = 0; n < 4; ++n) {
            acc[i0][n] = __builtin_amdgcn_mfma_f32_16x16x32_bf16(aa[0][kk], bfr[n][kk], acc[i0][n], 0, 0, 0);
            acc[i1][n] = __builtin_amdgcn_mfma_f32_16x16x32_bf16(aa[1][kk], bfr[n][kk], acc[i1][n], 0, 0, 0);
        }
    __builtin_amdgcn_s_setprio(0);
}

// ---------------- fused QKV GEMM (C = x @ W^T + b), bf16 MFMA ----------------
// 256x256 tile, BK=64, 8 waves (2x4), 2-barrier-per-tile pipelined schedule,
// A triple-buffered / B double-buffered staging (160 KiB LDS).
// wsel==0 (Q): epilogue computes sparsity scores, Q never stored.
//
// LDS map (bytes): A bufs 0/32768/65536 (t%3); B bufs 98304/131072 (t&1).
//   Each tile buf: half(128 rows) at +0/+16384, row-major [128][128B];
//   swizzle: data (r,c) at slot c^((r&7)<<4).
__global__ __launch_bounds__(512, 2) void k_gemm_qkv(
    const unsigned short* __restrict__ xb, const unsigned short* __restrict__ wb,
    const float* __restrict__ bq, const float* __restrict__ bk, const float* __restrict__ bv,
    unsigned short* __restrict__ Kb, unsigned short* __restrict__ Vb,
    float* __restrict__ scores)
{
    extern __shared__ char ldsb[];
    int bid = blockIdx.x;
    int mt = bid / 12, ntile = bid % 12;          // 12 blocks share one x-panel
    int wsel = ntile >> 2, ntq = ntile & 3;
    int tid = threadIdx.x, wid = tid >> 6, lane = tid & 63;
    int wm = wid >> 2, wn = wid & 3;              // wave -> 128x64 output
    int ml = lane & 15, quad = lane >> 4;

    const char* xg = (const char*)(xb + (size_t)mt * 256 * 1024);
    const char* wg = (const char*)(wb + (size_t)ntile * 256 * 1024);
    // A(h,t): xg + h*262144 + t*128 ; B(h,t): wg + h*262144 + t*128

    // staging lane constants (pre-swizzled global source)
    int rg0  = wid * 2;
    int rsub = lane >> 3;                         // row within 8-row group
    int cswz = ((lane & 7) ^ rsub) << 4;          // swizzled 16B col slot

#define STAGE(gbase_, roff_) do {                                          \
        const char* _g = (gbase_) + (size_t)(rg0 * 8 + rsub) * 2048 + cswz; \
        char* _l = ldsb + (roff_) + rg0 * 1024;                             \
        async16(_g, _l);                                                    \
        async16(_g + 8 * 2048, _l + 1024);                                  \
    } while (0)

    // ds_read lane constants: addr = base + m*2048 + (q0 ^ (kk<<6))
    int q0  = (quad * 16) ^ ((ml & 7) << 4);
    int qk0 = q0, qk1 = q0 ^ 64;
    int aconst = wm * 16384 + ml * 128;
    int bconst = (wn >> 1) * 16384 + (wn & 1) * 8192 + ml * 128;

    f32x4 acc[8][4] = {};

    // ---- prologue: A0, B0, A1, B1 (16 loads) -> vmcnt(8) drains A0,B0
    STAGE(xg,                0);
    STAGE(xg + 262144,       16384);
    STAGE(wg,                98304);
    STAGE(wg + 262144,       98304 + 16384);
    STAGE(xg + 128,          32768);
    STAGE(xg + 262144 + 128, 32768 + 16384);
    STAGE(wg + 128,          131072);
    STAGE(wg + 262144 + 128, 131072 + 16384);
    asm volatile("s_waitcnt vmcnt(8)" ::: "memory");
    __builtin_amdgcn_s_barrier();
    asm volatile("" ::: "memory");

    int abase = 0;                                // (t%3)*32768
    int sbase = 65536;                            // ((t+2)%3)*32768
    for (int t = 0; t < 16; ++t) {
        int bbase = 98304 + ((t & 1) << 15);
        const char* A_ = ldsb + abase + aconst;
        const char* B_ = ldsb + bbase + bconst;
        s16x8 bfr[4][2];
#pragma unroll
        for (int n = 0; n < 4; ++n) {
            bfr[n][0] = *(const s16x8*)(B_ + n * 2048 + qk0);
            bfr[n][1] = *(const s16x8*)(B_ + n * 2048 + qk1);
        }
        s16x8 af[2][2], ag[2][2];
        rdA(af, A_, 0, qk0, qk1);
        // p0/p1: stage A(t+2) into buffer (t+2)%3 — its last reader was tile
        // t-1, whose ds_reads retired before the end-of-(t-1) barrier: safe.
        if (t < 14) STAGE(xg + (size_t)(t + 2) * 128, sbase);
        rdA(ag, A_, 2, qk0, qk1);                 // prefetch p1 under p0-MFMA
        mfma8(acc, 0, 1, af, bfr);                // p0
        if (t < 14) STAGE(xg + 262144 + (size_t)(t + 2) * 128, sbase + 16384);
        rdA(af, A_, 4, qk0, qk1);                 // prefetch p2 under p1-MFMA
        mfma8(acc, 2, 3, ag, bfr);                // p1
        // -- mid-tile barrier (B-region protect): arrival implies every
        //    wave's B ds_reads retired (consumed by its p0/p1 MFMAs)
        asm volatile("" ::: "memory");
        __builtin_amdgcn_s_barrier();
        asm volatile("" ::: "memory");
        // p2/p3: stage B(t+2) into the current-parity B region (now free)
        if (t < 14) STAGE(wg + (size_t)(t + 2) * 128, bbase);
        rdA(ag, A_, 6, qk0, qk1);                 // prefetch p3 under p2-MFMA
        mfma8(acc, 4, 5, af, bfr);                // p2
        if (t < 14) STAGE(wg + 262144 + (size_t)(t + 2) * 128, bbase + 16384);
        mfma8(acc, 6, 7, ag, bfr);                // p3
        // -- tile boundary: drain A(t+1),B(t+1) (issued one tile ago);
        //    leaves tile-t's own 8 stages (A(t+2),B(t+2)) in flight
        if (t < 15) {
            if (t <= 13)      asm volatile("s_waitcnt vmcnt(8)" ::: "memory");
            else              asm volatile("s_waitcnt vmcnt(0)" ::: "memory");
            asm volatile("" ::: "memory");
            __builtin_amdgcn_s_barrier();
            asm volatile("" ::: "memory");
        }
        abase = abase == 65536 ? 0 : abase + 32768;
        sbase = sbase == 65536 ? 0 : sbase + 32768;
    }
#undef STAGE

    float bvv[4];
    const float* bias = wsel == 0 ? bq : (wsel == 1 ? bk : bv);
    int colbase = ntq * 256 + wn * 64;
#pragma unroll
    for (int n = 0; n < 4; ++n) bvv[n] = bias[colbase + n * 16 + ml];

    if (wsel == 0) {
        // score epilogue: quad's 16 lanes hold full 64-wide Q rows of head hh
        int hh = ntq * 4 + wn;
#pragma unroll
        for (int m = 0; m < 8; ++m) {
#pragma unroll
            for (int r = 0; r < 4; ++r) {
                float q0v = acc[m][0][r] + bvv[0];
                float q1v = acc[m][1][r] + bvv[1];
                float q2v = acc[m][2][r] + bvv[2];
                float q3v = acc[m][3][r] + bvv[3];
                float mx = fmaxf(fmaxf(q0v, q1v), fmaxf(q2v, q3v));
                float sm = q0v + q1v + q2v + q3v;
                float ss = q0v * q0v + q1v * q1v + q2v * q2v + q3v * q3v;
#pragma unroll
                for (int off = 1; off < 16; off <<= 1) {
                    mx = fmaxf(mx, __shfl_xor(mx, off));
                    sm += __shfl_xor(sm, off);
                    ss += __shfl_xor(ss, off);
                }
                float e0 = expf(q0v - mx), e1 = expf(q1v - mx);
                float e2 = expf(q2v - mx), e3 = expf(q3v - mx);
                float S = e0 + e1 + e2 + e3;
#pragma unroll
                for (int off = 1; off < 16; off <<= 1) S += __shfl_xor(S, off);
                float is = 1.f / S;
                float p0 = e0 * is, p1 = e1 * is, p2 = e2 * is, p3 = e3 * is;
                float ent = -p0 * logf(p0 + 1e-9f) - p1 * logf(p1 + 1e-9f)
                            - p2 * logf(p2 + 1e-9f) - p3 * logf(p3 + 1e-9f);
                float mean = sm * (1.f / 64.f);
                float d0 = q0v - mean, d1 = q1v - mean, d2 = q2v - mean, d3 = q3v - mean;
                float var = d0 * d0 + d1 * d1 + d2 * d2 + d3 * d3;
#pragma unroll
                for (int off = 1; off < 16; off <<= 1) {
                    ent += __shfl_xor(ent, off);
                    var += __shfl_xor(var, off);
                }
                if (ml == 0) {
                    float sc = 0.5f * sqrtf(ss) + 0.3f * ent + 0.2f * (var * (1.f / 63.f));
                    int row = mt * 256 + wm * 128 + m * 16 + quad * 4 + r;
                    scores[(size_t)(((row >> 13) << 4) + hh) * 8192 + (row & 8191)] = sc;
                }
            }
        }
    } else {
        unsigned short* outp = wsel == 1 ? Kb : Vb;
#pragma unroll
        for (int m = 0; m < 8; ++m) {
            int grow0 = mt * 256 + wm * 128 + m * 16 + quad * 4;
#pragma unroll
            for (int n = 0; n < 4; ++n) {
                int gcol = colbase + n * 16 + ml;
#pragma unroll
                for (int r = 0; r < 4; ++r)
                    outp[(size_t)(grow0 + r) * 1024 + gcol] = f2bf(acc[m][n][r] + bvv[n]);
            }
        }
    }
}

// ---------------- top-16 candidates + (h==0) u-stats, per pair ----------------
__global__ __launch_bounds__(1024) void k_cand(const float* __restrict__ scores,
                                               int* __restrict__ cand, int* __restrict__ u)
{
    int pair = blockIdx.x; int t = threadIdx.x;
    __shared__ float  s_lds[8192];
    __shared__ double dred[1024];
    __shared__ float  wvv[16];
    __shared__ int    wii[16];
    const float* sp = scores + (size_t)pair * 8192;
    for (int i = t; i < 8192; i += 1024) s_lds[i] = sp[i];
    __syncthreads();

    if ((pair & 15) == 0) {     // head 0: compute u[b] from these scores
        double a0 = 0;
#pragma unroll
        for (int k = 0; k < 8; ++k) a0 += (double)s_lds[t + k * 1024];
        dred[t] = a0; __syncthreads();
        for (int st = 512; st > 0; st >>= 1) { if (t < st) dred[t] += dred[t + st]; __syncthreads(); }
        double mean = dred[0] / 8192.0;
        __syncthreads();
        double a1 = 0;
#pragma unroll
        for (int k = 0; k < 8; ++k) { double d = (double)s_lds[t + k * 1024] - mean; a1 += d * d; }
        dred[t] = a1; __syncthreads();
        for (int st = 512; st > 0; st >>= 1) { if (t < st) dred[t] += dred[t + st]; __syncthreads(); }
        if (t == 0) {
            double sd = sqrt(dred[0] / 8191.0);
            double ratio = sd / (mean + 1e-6) * 10.0;
            int f = (int)rint(ratio);
            f = f < 3 ? 3 : (f > 10 ? 10 : f);
            u[pair >> 4] = f;
        }
        __syncthreads();
    }

    for (int it = 0; it < 16; ++it) {
        float bv = -1e30f; int bi = 0x7fffffff;
#pragma unroll
        for (int k = 0; k < 8; ++k) {
            int i = t + k * 1024;
            float v = s_lds[i];
            if (v > bv || (v == bv && i < bi)) { bv = v; bi = i; }
        }
#pragma unroll
        for (int off = 32; off > 0; off >>= 1) {
            float ov = __shfl_down(bv, off);
            int   oi = __shfl_down(bi, off);
            if (ov > bv || (ov == bv && oi < bi)) { bv = ov; bi = oi; }
        }
        if ((t & 63) == 0) { wvv[t >> 6] = bv; wii[t >> 6] = bi; }
        __syncthreads();
        if (t == 0) {
            float fv = wvv[0]; int fi = wii[0];
            for (int k = 1; k < 16; ++k)
                if (wvv[k] > fv || (wvv[k] == fv && wii[k] < fi)) { fv = wvv[k]; fi = wii[k]; }
            cand[pair * 16 + it] = fi;
            s_lds[fi] = -1e30f;
        }
        __syncthreads();
    }
}

// ---------------- exact fp64 rescore, one block per (pair,candidate) ----------------
__global__ __launch_bounds__(256) void k_rescore(
    const int* __restrict__ cand, const float* __restrict__ x,
    const float* __restrict__ wq, const float* __restrict__ bq,
    double* __restrict__ cscore, float* __restrict__ cq)
{
    int bid = blockIdx.x;             // pair*16 + c
    int pair = bid >> 4;
    int b = pair >> 4, h = pair & 15;
    int t = threadIdx.x;
    __shared__ float  xrow[1024];
    __shared__ double dred[256];
    __shared__ double qrow[64];

    int l = cand[bid];
    const float* xr = x + ((size_t)b * 8192 + l) * 1024;
    for (int i = t; i < 1024; i += 256) xrow[i] = xr[i];
    __syncthreads();

    int d = t >> 2, ks = t & 3;
    const float* wr = wq + (size_t)(h * 64 + d) * 1024 + ks * 256;
    const float* xs = xrow + ks * 256;
    double p = 0;
    for (int k = 0; k < 256; k += 4) {
        float4 w4 = *(const float4*)(wr + k);
        float4 x4 = *(const float4*)(xs + k);
        p += (double)w4.x * x4.x + (double)w4.y * x4.y +
             (double)w4.z * x4.z + (double)w4.w * x4.w;
    }
    dred[t] = p; __syncthreads();
    if ((t & 3) == 0)
        qrow[t >> 2] = dred[t] + dred[t + 1] + dred[t + 2] + dred[t + 3] + (double)bq[h * 64 + (t >> 2)];
    __syncthreads();

    if (t < 64) {
        double q = qrow[t];
        cq[(size_t)bid * 64 + t] = (float)q;
        double m = q;
#pragma unroll
        for (int off = 32; off > 0; off >>= 1) m = fmax(m, __shfl_down(m, off));
        m = __shfl(m, 0);
        double e = exp(q - m);
        double sum = q, sumsq = q * q, S = e;
#pragma unroll
        for (int off = 32; off > 0; off >>= 1) {
            sum += __shfl_down(sum, off);
            sumsq += __shfl_down(sumsq, off);
            S += __shfl_down(S, off);
        }
        sum = __shfl(sum, 0); sumsq = __shfl(sumsq, 0); S = __shfl(S, 0);
        double pp = e / S;
        double entc = -pp * log(pp + 1e-9);
        double mean = sum / 64.0;
        double dv = q - mean;
        double varc = dv * dv;
#pragma unroll
        for (int off = 32; off > 0; off >>= 1) {
            entc += __shfl_down(entc, off);
            varc += __shfl_down(varc, off);
        }
        if (t == 0)
            cscore[bid] = 0.5 * sqrt(sumsq) + 0.3 * entc + 0.2 * (varc / 63.0);
    }
}

// ---------------- top-10-of-16 select ----------------
__global__ void k_select(const int* __restrict__ cand, const double* __restrict__ cscore,
                         const float* __restrict__ cq,
                         int* __restrict__ sel, float* __restrict__ selq)
{
    int pair = blockIdx.x; int t = threadIdx.x;   // 64 threads
    __shared__ int order[10];
    if (t == 0) {
        bool used[16] = {};
        for (int r = 0; r < 10; ++r) {
            int best = -1;
            for (int c = 0; c < 16; ++c) {
                if (used[c]) continue;
                int ic = pair * 16 + c;
                if (best < 0 || cscore[ic] > cscore[pair * 16 + best] ||
                    (cscore[ic] == cscore[pair * 16 + best] && cand[ic] < cand[pair * 16 + best]))
                    best = c;
            }
            used[best] = true; order[r] = best;
            sel[pair * 10 + r] = cand[pair * 16 + best];
        }
    }
    __syncthreads();
    for (int r = 0; r < 10; ++r)
        selq[((size_t)pair * 10 + r) * 64 + t] = cq[((size_t)pair * 16 + order[r]) * 64 + t];
}

// ---------------- attention partials: one K/V pass, 256-row chunks ----------------
__global__ __launch_bounds__(256) void k_attn_part(
    const unsigned short* __restrict__ Kb, const unsigned short* __restrict__ Vb,
    const float* __restrict__ selq, const int* __restrict__ u,
    float* __restrict__ part)
{
    int bid = blockIdx.x;
    int pair = bid >> 5, chunk = bid & 31;
    int b = pair >> 4, h = pair & 15;
    int uu = u[b];
    int t = threadIdx.x, wave = t >> 6, lane = t & 63;

    __shared__ float q_sh[10][64];
    __shared__ float w_sh[10][256];
    __shared__ unsigned short V_sh[256][68];
    __shared__ float mc_sh[10][2], Sc_sh[10][2];

    size_t kvbase = ((size_t)b * 8192 + (size_t)chunk * 256) * 1024 + h * 64;

    for (int i = t; i < uu * 64; i += 256)
        q_sh[i >> 6][i & 63] = selq[(size_t)pair * 640 + i] * 0.125f;

    const u16x8* kr = (const u16x8*)(Kb + kvbase + (size_t)t * 1024);
    const u16x8* vr = (const u16x8*)(Vb + kvbase + (size_t)t * 1024);
    u16x8 vreg[8];
#pragma unroll
    for (int k8 = 0; k8 < 8; ++k8) vreg[k8] = vr[k8];
#pragma unroll
    for (int k8 = 0; k8 < 8; ++k8) {
        *(u16x4*)&V_sh[t][k8 * 8]     = { vreg[k8][0], vreg[k8][1], vreg[k8][2], vreg[k8][3] };
        *(u16x4*)&V_sh[t][k8 * 8 + 4] = { vreg[k8][4], vreg[k8][5], vreg[k8][6], vreg[k8][7] };
    }
    float krow[64];
#pragma unroll
    for (int k8 = 0; k8 < 8; ++k8) {
        u16x8 kv = kr[k8];
#pragma unroll
        for (int e = 0; e < 8; ++e) krow[k8 * 8 + e] = bf2f(kv[e]);
    }
    __syncthreads();

    for (int rr = 0; rr < uu; ++rr) {
        const float4* qp = (const float4*)q_sh[rr];
        float acc = 0.f;
#pragma unroll
        for (int i4 = 0; i4 < 16; ++i4) {
            float4 q4 = qp[i4];
            acc += q4.x * krow[i4 * 4] + q4.y * krow[i4 * 4 + 1] +
                   q4.z * krow[i4 * 4 + 2] + q4.w * krow[i4 * 4 + 3];
        }
        w_sh[rr][t] = acc;
    }
    __syncthreads();

    for (int rr = wave; rr < uu; rr += 4) {
        float4 wv = *(const float4*)&w_sh[rr][lane * 4];
        float m4 = fmaxf(fmaxf(wv.x, wv.y), fmaxf(wv.z, wv.w));
#pragma unroll
        for (int off = 16; off > 0; off >>= 1) m4 = fmaxf(m4, __shfl_xor(m4, off));
        float e0 = expf(wv.x - m4), e1 = expf(wv.y - m4);
        float e2 = expf(wv.z - m4), e3 = expf(wv.w - m4);
        float s = e0 + e1 + e2 + e3;
#pragma unroll
        for (int off = 16; off > 0; off >>= 1) s += __shfl_xor(s, off);
        float4 ev = { e0, e1, e2, e3 };
        *(float4*)&w_sh[rr][lane * 4] = ev;
        if ((lane & 31) == 0) { int jh = lane >> 5; mc_sh[rr][jh] = m4; Sc_sh[rr][jh] = s; }
    }
    __syncthreads();

    int jh = t >> 7, tt = t & 127, dp = tt & 31;
    for (int rr = tt >> 5; rr < uu; rr += 4) {
        float o0 = 0.f, o1 = 0.f;
        int j0 = jh * 128;
        for (int j = j0; j < j0 + 128; j += 4) {
            float4 w4 = *(const float4*)&w_sh[rr][j];
#pragma unroll
            for (int jj = 0; jj < 4; ++jj) {
                unsigned v = *(const unsigned*)&V_sh[j + jj][dp * 2];
                float w1 = jj == 0 ? w4.x : (jj == 1 ? w4.y : (jj == 2 ? w4.z : w4.w));
                o0 += w1 * __uint_as_float(v << 16);
                o1 += w1 * __uint_as_float(v & 0xffff0000u);
            }
        }
        float* pp = part + (((size_t)pair * 10 + rr) * 64 + chunk * 2 + jh) * 66;
        float2 o2 = { o0, o1 };
        *(float2*)&pp[2 + dp * 2] = o2;
        if (dp == 0) { pp[0] = mc_sh[rr][jh]; pp[1] = Sc_sh[rr][jh]; }
    }
}

// ---------------- output: broadcast bias ----------------
__global__ void k_bias(const float* __restrict__ bo, float* __restrict__ out) {
    size_t i = (size_t)blockIdx.x * 256 + threadIdx.x;   // 8388608 float4s
    int col4 = (int)(i & 255);
    ((float4*)out)[i] = ((const float4*)bo)[col4];
}

// ---------------- fused merge + sparse scatter ----------------
__global__ __launch_bounds__(256) void k_mergescatter(
    const float* __restrict__ part, const int* __restrict__ sel,
    const int* __restrict__ u, const float* __restrict__ wo,
    float* __restrict__ out)
{
    int idx = blockIdx.x; int pair = idx / 10; int r = idx % 10;
    int b = pair >> 4, h = pair & 15;
    if (r >= u[b]) return;
    int t = threadIdx.x;
    __shared__ float a_sh[64];
    if (t < 64) {
        const float* base = part + ((size_t)pair * 10 + r) * 64 * 66;
        float m = -1e30f;
        for (int c = 0; c < 64; ++c) m = fmaxf(m, base[c * 66]);
        float S = 0, o = 0;
        for (int c = 0; c < 64; ++c) {
            float f = expf(base[c * 66] - m);
            S += f * base[c * 66 + 1];
            o += f * base[c * 66 + 2 + t];
        }
        a_sh[t] = o / S;
    }
    __syncthreads();
    int l = sel[pair * 10 + r];
    float* orow = out + ((size_t)b * 8192 + l) * 1024;
    for (int j = t; j < 1024; j += 256) {
        const float* wr = wo + (size_t)j * 1024 + h * 64;
        float acc = 0;
#pragma unroll
        for (int d = 0; d < 64; d += 4) {
            float4 w4 = *(const float4*)(wr + d);
            acc += a_sh[d] * w4.x + a_sh[d + 1] * w4.y + a_sh[d + 2] * w4.z + a_sh[d + 3] * w4.w;
        }
        atomicAdd(orow + j, acc);
    }
}

// ---------------- workspace layout ----------------
static constexpr size_t OFF_XB    = 0;                        // 67108864
static constexpr size_t OFF_WB    = OFF_XB + 67108864;        // 6291456
static constexpr size_t OFF_KB    = OFF_WB + 6291456;         // 67108864
static constexpr size_t OFF_VB    = OFF_KB + 67108864;        // 67108864
static constexpr size_t OFF_SC    = OFF_VB + 67108864;        // 2097152
static constexpr size_t OFF_U     = OFF_SC + 2097152;         // 256
static constexpr size_t OFF_SEL   = OFF_U + 256;              // 4096
static constexpr size_t OFF_SELQ  = OFF_SEL + 4096;           // 163840
static constexpr size_t OFF_PART  = OFF_SELQ + 163840;        // 64*10*64*66*4 = 10813440
static constexpr size_t OFF_CAND  = OFF_PART + 10813440;      // 4096
static constexpr size_t OFF_CSC   = OFF_CAND + 4096;          // 8192
static constexpr size_t OFF_CQ    = OFF_CSC + 8192;           // 262144
static constexpr size_t WS_NEED   = OFF_CQ + 262144;

extern "C" void kernel_launch(void* const* d_in, const int* in_sizes, int n_in,
                              void* d_out, int out_size, void* d_ws, size_t ws_size,
                              hipStream_t stream)
{
    const float* x  = (const float*)d_in[0];
    const float* wq = (const float*)d_in[1];
    const float* bq = (const float*)d_in[2];
    const float* wk = (const float*)d_in[3];
    const float* bk = (const float*)d_in[4];
    const float* wv = (const float*)d_in[5];
    const float* bv = (const float*)d_in[6];
    const float* wo = (const float*)d_in[7];
    const float* bo = (const float*)d_in[8];
    float* out = (float*)d_out;

    if (ws_size < WS_NEED) return;

    char* ws = (char*)d_ws;
    unsigned short* xb = (unsigned short*)(ws + OFF_XB);
    unsigned short* wb = (unsigned short*)(ws + OFF_WB);
    unsigned short* Kb = (unsigned short*)(ws + OFF_KB);
    unsigned short* Vb = (unsigned short*)(ws + OFF_VB);
    float*  scores = (float*)(ws + OFF_SC);
    int*    u      = (int*)(ws + OFF_U);
    int*    sel    = (int*)(ws + OFF_SEL);
    float*  selq   = (float*)(ws + OFF_SELQ);
    float*  part   = (float*)(ws + OFF_PART);
    int*    cand   = (int*)(ws + OFF_CAND);
    double* cscore = (double*)(ws + OFF_CSC);
    float*  cq     = (float*)(ws + OFF_CQ);

    k_conv        <<<35840, 256,  0,      stream>>>(x, wq, wk, wv, xb, wb);
    k_gemm_qkv    <<<1536,  512,  163840, stream>>>(xb, wb, bq, bk, bv, Kb, Vb, scores);
    k_cand        <<<64,    1024, 0,      stream>>>(scores, cand, u);
    k_rescore     <<<1024,  256,  0,      stream>>>(cand, x, wq, bq, cscore, cq);
    k_select      <<<64,    64,   0,      stream>>>(cand, cscore, cq, sel, selq);
    k_attn_part   <<<2048,  256,  0,      stream>>>(Kb, Vb, selq, u, part);
    k_bias        <<<32768, 256,  0,      stream>>>(bo, out);
    k_mergescatter<<<640,   256,  0,      stream>>>(part, sel, u, wo, out);
}